// Round 1
// baseline (1439.123 us; speedup 1.0000x reference)
//
#include <hip/hip_runtime.h>
#include <math.h>

// Shapes (compile-time constants from the reference)
// B=8, N=1024, D=64, H=4, DH=16, DI=128, DS=64, DTR=4, MAXP=512

__device__ __forceinline__ float wsum64(float v){
#pragma unroll
  for(int m=32;m>0;m>>=1) v += __shfl_xor(v, m, 64);
  return v;
}
__device__ __forceinline__ float wmax64(float v){
#pragma unroll
  for(int m=32;m>0;m>>=1) v = fmaxf(v, __shfl_xor(v, m, 64));
  return v;
}
__device__ __forceinline__ float silu_f(float x){ return x / (1.f + __expf(-x)); }

// ---------------------------------------------------------------------------
// K1: LN1 + Q / KV projection.  wave per token.
__global__ __launch_bounds__(256) void k_ln1_qkv(
    const float* __restrict__ x, const float* __restrict__ w1, const float* __restrict__ b1,
    const float* __restrict__ Wq, const float* __restrict__ Wkv,
    float* __restrict__ qb, float* __restrict__ kb, float* __restrict__ vb){
  int lane = threadIdx.x & 63, warp = threadIdx.x >> 6;
  int token = blockIdx.x*4 + warp;            // 0..8191
  __shared__ float xt[4][64];
  float xv = x[(size_t)token*64 + lane];
  float mean = wsum64(xv) * 0.015625f;
  float dlt = xv - mean;
  float var = wsum64(dlt*dlt) * 0.015625f;
  float xn = dlt * rsqrtf(var + 1e-5f) * w1[lane] + b1[lane];
  xt[warp][lane] = xn;
  __syncthreads();
  float aq=0.f, ak=0.f, av=0.f;
#pragma unroll 4
  for(int dd=0; dd<64; ++dd){
    float xd = xt[warp][dd];
    aq += xd * Wq[dd*64 + lane];
    ak += xd * Wkv[dd*128 + lane];
    av += xd * Wkv[dd*128 + 64 + lane];
  }
  int b = token >> 10, i = token & 1023;
  int h = lane >> 4, dh = lane & 15;
  size_t o = (((size_t)(b*4 + h))*1024 + i)*16 + dh;   // (B,H,N,DH)
  qb[o]=aq; kb[o]=ak; vb[o]=av;
}

// ---------------------------------------------------------------------------
// K2: attention. block = 256 threads handles 8 query rows of one (b,h).
#define TI 8
__global__ __launch_bounds__(256) void k_attn(
    const float* __restrict__ qb, const float* __restrict__ kb, const float* __restrict__ vb,
    const int* __restrict__ dmask, const float* __restrict__ rel,
    float* __restrict__ attn_raw){
  int tid = threadIdx.x;
  int bh  = blockIdx.y;                 // 0..31
  int it0 = blockIdx.x * TI;
  int b = bh >> 2, h = bh & 3;
  __shared__ float qs[TI][16];
  __shared__ float parr[TI*1024];
  __shared__ float redm[4][TI];
  __shared__ float reds[4][TI];
  __shared__ float ssumS[TI];
  __shared__ float accred[16][16][TI];
  if (tid < TI*16){
    int ii = tid >> 4, c = tid & 15;
    qs[ii][c] = qb[((size_t)bh*1024 + it0 + ii)*16 + c];
  }
  __syncthreads();

  float s[TI][4];
  float lm[TI];
#pragma unroll
  for(int ii=0; ii<TI; ++ii) lm[ii] = -3.0e38f;
  const float* kbase = kb + (size_t)bh*1024*16;
#pragma unroll
  for(int r=0;r<4;++r){
    int j = tid + 256*r;
    const float4* kr = (const float4*)(kbase + (size_t)j*16);
    float4 k0=kr[0],k1=kr[1],k2=kr[2],k3=kr[3];
#pragma unroll
    for(int ii=0; ii<TI; ++ii){
      int i = it0 + ii;
      int dist = i - j; dist = dist < -512 ? -512 : (dist > 512 ? 512 : dist); dist += 512;
      const float4* rp = (const float4*)(rel + (size_t)dist*16);
      float4 r0=rp[0],r1=rp[1],r2=rp[2],r3=rp[3];
      float acc =
        qs[ii][ 0]*(k0.x+r0.x)+qs[ii][ 1]*(k0.y+r0.y)+qs[ii][ 2]*(k0.z+r0.z)+qs[ii][ 3]*(k0.w+r0.w)
       +qs[ii][ 4]*(k1.x+r1.x)+qs[ii][ 5]*(k1.y+r1.y)+qs[ii][ 6]*(k1.z+r1.z)+qs[ii][ 7]*(k1.w+r1.w)
       +qs[ii][ 8]*(k2.x+r2.x)+qs[ii][ 9]*(k2.y+r2.y)+qs[ii][10]*(k2.z+r2.z)+qs[ii][11]*(k2.w+r2.w)
       +qs[ii][12]*(k3.x+r3.x)+qs[ii][13]*(k3.y+r3.y)+qs[ii][14]*(k3.z+r3.z)+qs[ii][15]*(k3.w+r3.w);
      int mk = dmask[((size_t)bh*1024 + i)*1024 + j];
      float sv = 0.25f*acc + (mk ? -1.0e12f : 0.0f);
      s[ii][r] = sv;
      lm[ii] = fmaxf(lm[ii], sv);
    }
  }
  int lane = tid & 63, warp = tid >> 6;
#pragma unroll
  for(int ii=0; ii<TI; ++ii){
    float v = wmax64(lm[ii]);
    if (lane==0) redm[warp][ii] = v;
  }
  __syncthreads();
  float rowmax[TI], lsum[TI];
#pragma unroll
  for(int ii=0; ii<TI; ++ii){
    rowmax[ii] = fmaxf(fmaxf(redm[0][ii], redm[1][ii]), fmaxf(redm[2][ii], redm[3][ii]));
    lsum[ii] = 0.f;
  }
#pragma unroll
  for(int r=0;r<4;++r){
    int j = tid + 256*r;
#pragma unroll
    for(int ii=0; ii<TI; ++ii){
      float p = __expf(s[ii][r] - rowmax[ii]);
      parr[ii*1024 + j] = p;
      lsum[ii] += p;
    }
  }
#pragma unroll
  for(int ii=0;ii<TI;++ii){
    float v = wsum64(lsum[ii]);
    if(lane==0) reds[warp][ii]=v;
  }
  __syncthreads();
  if (tid < TI) ssumS[tid] = reds[0][tid]+reds[1][tid]+reds[2][tid]+reds[3][tid];

  // PV phase: thread = (g = tid>>4 over j-groups of 64, c = tid&15 over head dim)
  int c = tid & 15, g = tid >> 4;
  float acc[TI];
#pragma unroll
  for(int ii=0;ii<TI;++ii) acc[ii]=0.f;
  const float* vbase = vb + (size_t)bh*1024*16;
#pragma unroll 4
  for(int jj=0;jj<64;++jj){
    int jr = (jj + g*16) & 63;       // bank rotation: keeps LDS aliasing at free 2-way
    int j = g*64 + jr;
    float vv = vbase[(size_t)j*16 + c];
#pragma unroll
    for(int ii=0;ii<TI;++ii) acc[ii] += parr[ii*1024 + j]*vv;
  }
#pragma unroll
  for(int ii=0;ii<TI;++ii) accred[g][c][ii]=acc[ii];
  __syncthreads();
  if (tid < 16*TI){
    int ii = tid >> 4, cc = tid & 15;
    float tot = 0.f;
#pragma unroll
    for(int gg=0; gg<16; ++gg) tot += accred[gg][cc][ii];
    attn_raw[((size_t)b*1024 + it0 + ii)*64 + h*16 + cc] = tot / ssumS[ii];
  }
}

// ---------------------------------------------------------------------------
// K3: Wo proj + double residual + LN2 + W_in (u0, silu(z)). wave per token.
__global__ __launch_bounds__(256) void k_post_attn(
    const float* __restrict__ x, const float* __restrict__ attn_raw,
    const float* __restrict__ Wo, const float* __restrict__ bo,
    const float* __restrict__ ln2w, const float* __restrict__ ln2b,
    const float* __restrict__ W_in,
    float* __restrict__ x2, float* __restrict__ u0, float* __restrict__ zsarr){
  int lane = threadIdx.x & 63, warp = threadIdx.x >> 6;
  int token = blockIdx.x*4 + warp;
  __shared__ float ar[4][64];
  __shared__ float lnv[4][64];
  ar[warp][lane] = attn_raw[(size_t)token*64 + lane];
  __syncthreads();
  float acc = bo[lane];
#pragma unroll 4
  for(int dd=0;dd<64;++dd) acc += ar[warp][dd]*Wo[dd*64+lane];
  float t = 2.f*x[(size_t)token*64+lane] + acc;    // x + (attn_out + x)
  x2[(size_t)token*64+lane] = t;
  float mean = wsum64(t)*0.015625f;
  float dlt = t-mean;
  float var = wsum64(dlt*dlt)*0.015625f;
  float ln = dlt*rsqrtf(var+1e-5f)*ln2w[lane]+ln2b[lane];
  lnv[warp][lane]=ln;
  __syncthreads();
  float a0=0.f,a1=0.f,a2=0.f,a3=0.f;
#pragma unroll 4
  for(int dd=0;dd<64;++dd){
    float xd = lnv[warp][dd];
    const float* wr = W_in + dd*256;
    a0 += xd*wr[lane]; a1 += xd*wr[lane+64]; a2 += xd*wr[lane+128]; a3 += xd*wr[lane+192];
  }
  u0[(size_t)token*128 + lane] = a0;
  u0[(size_t)token*128 + 64 + lane] = a1;
  zsarr[(size_t)token*128 + lane] = silu_f(a2);
  zsarr[(size_t)token*128 + 64 + lane] = silu_f(a3);
}

// ---------------------------------------------------------------------------
// K4: causal depthwise conv4 + silu + x-proj(132) + softplus dt. 128 lanes/token.
__global__ __launch_bounds__(256) void k_conv_proj(
    const float* __restrict__ u0, const float* __restrict__ conv_w, const float* __restrict__ conv_b,
    const float* __restrict__ W_xproj, const float* __restrict__ W_dt, const float* __restrict__ b_dt,
    float* __restrict__ uarr, float* __restrict__ Bmp, float* __restrict__ Cmp, float* __restrict__ dtarr){
  int sub = threadIdx.x >> 7, c = threadIdx.x & 127;
  int token = blockIdx.x*2 + sub;
  int b = token >> 10, i = token & 1023;
  __shared__ float us[2][128];
  __shared__ float dtin[2][4];
  float acc = conv_b[c];
#pragma unroll
  for(int k2=0;k2<4;++k2){
    int t2 = i - 3 + k2;
    if (t2 >= 0) acc += u0[((size_t)b*1024 + t2)*128 + c]*conv_w[c*4+k2];
  }
  float uv = silu_f(acc);
  uarr[(size_t)token*128 + c] = uv;
  us[sub][c] = uv;
  __syncthreads();
  float accA = 0.f, accB = 0.f;
  int cB = 128 + (c & 3);
#pragma unroll 4
  for(int dd=0; dd<128; ++dd){
    float xd = us[sub][dd];
    accA += xd * W_xproj[dd*132 + c];
    accB += xd * W_xproj[dd*132 + cB];
  }
  if (c < 4){ dtin[sub][c] = accA; Cmp[(size_t)token*64 + 60 + c] = accB; }
  else if (c < 68) Bmp[(size_t)token*64 + (c-4)] = accA;
  else             Cmp[(size_t)token*64 + (c-68)] = accA;
  __syncthreads();
  float dv = b_dt[c];
#pragma unroll
  for(int r2=0;r2<4;++r2) dv += dtin[sub][r2]*W_dt[r2*128 + c];
  dv = fmaxf(dv, 0.f) + log1pf(expf(-fabsf(dv)));   // softplus, stable
  dtarr[(size_t)token*128 + c] = dv;
}

// ---------------------------------------------------------------------------
// K5: selective scan. wave = (b,d), lane = s. 8-step load batching for MLP.
__global__ __launch_bounds__(256) void k_scan(
    const float* __restrict__ dtarr, const float* __restrict__ uarr,
    const float* __restrict__ Bmp, const float* __restrict__ Cmp,
    const float* __restrict__ zsarr, const float* __restrict__ A_log,
    const float* __restrict__ Dm, float* __restrict__ ymp){
  int lane = threadIdx.x & 63, warp = threadIdx.x >> 6;
  int g = blockIdx.x*4 + warp;          // 0..1023
  int b = g >> 7, d = g & 127;
  float A = -expf(A_log[d*64 + lane]);
  float Dv = Dm[d];
  const float* dtp = dtarr + (size_t)b*1024*128 + d;
  const float* up  = uarr  + (size_t)b*1024*128 + d;
  const float* zp  = zsarr + (size_t)b*1024*128 + d;
  const float* Bp  = Bmp   + (size_t)b*1024*64 + lane;
  const float* Cp  = Cmp   + (size_t)b*1024*64 + lane;
  float* yp        = ymp   + (size_t)b*1024*128 + d;
  float h = 0.f;
  for(int t0=0; t0<1024; t0+=8){
    float dtc[8], uc[8], Bc[8], Cc[8], zc[8];
#pragma unroll
    for(int r=0;r<8;++r){
      dtc[r]=dtp[(size_t)(t0+r)*128]; uc[r]=up[(size_t)(t0+r)*128];
      Bc[r]=Bp[(size_t)(t0+r)*64];    Cc[r]=Cp[(size_t)(t0+r)*64];
      zc[r]=zp[(size_t)(t0+r)*128];
    }
#pragma unroll
    for(int r=0;r<8;++r){
      float dt = dtc[r];
      h = h*__expf(dt*A) + dt*uc[r]*Bc[r];
      float y = wsum64(h*Cc[r]);
      if (lane==0) yp[(size_t)(t0+r)*128] = (y + uc[r]*Dv)*zc[r];
    }
  }
}

// ---------------------------------------------------------------------------
// K6: y @ W_out + leaky + group(4)-RMS-norm. wave per token.
__global__ __launch_bounds__(256) void k_wout(
    const float* __restrict__ ymp, const float* __restrict__ W_out,
    const float* __restrict__ gamma, float* __restrict__ marr){
  int lane = threadIdx.x & 63, warp = threadIdx.x >> 6;
  int token = blockIdx.x*4 + warp;
  __shared__ float ys[4][128];
  ys[warp][lane]      = ymp[(size_t)token*128 + lane];
  ys[warp][lane+64]   = ymp[(size_t)token*128 + 64 + lane];
  __syncthreads();
  float acc = 0.f;
#pragma unroll 4
  for(int dd=0; dd<128; ++dd) acc += ys[warp][dd]*W_out[dd*64 + lane];
  acc = acc >= 0.f ? acc : 0.01f*acc;                 // leaky relu
  float ss = acc*acc;
#pragma unroll
  for(int m=1;m<16;m<<=1) ss += __shfl_xor(ss, m, 64); // 16-lane group sum
  float rms = sqrtf(ss)*0.25f;                         // * dpg^-0.5 (dpg=16)
  marr[(size_t)token*64 + lane] = acc/(rms + 1e-5f)*gamma[lane];
}

// ---------------------------------------------------------------------------
// K7: GLU conv1 -> h2[b, tau(0..1026), i(0..255)], tau-major for coalescing.
__global__ __launch_bounds__(256) void k_h2(
    const float* __restrict__ marr, const float* __restrict__ c1w,
    const float* __restrict__ c1b, float* __restrict__ h2){
  int b = blockIdx.y;
  int t0 = blockIdx.x * 16;
  int tid = threadIdx.x;
  __shared__ float ms[19][64];
  for(int l = tid; l < 19*64; l += 256){
    int row = l >> 6, cc = l & 63;
    int t = t0 - 3 + row;
    ms[row][cc] = (t >= 0 && t < 1024) ? marr[((size_t)b*1024 + t)*64 + cc] : 0.f;
  }
  __syncthreads();
  int i = tid;
  float acc1[16], acc2[16];
#pragma unroll
  for(int tl=0;tl<16;++tl){ acc1[tl]=0.f; acc2[tl]=0.f; }
  const float* w1 = c1w + (size_t)i*256;
  const float* w2 = c1w + (size_t)(i+256)*256;
  for(int cc=0; cc<64; ++cc){
    float mv[19];
#pragma unroll
    for(int r2=0;r2<19;++r2) mv[r2] = ms[r2][cc];
#pragma unroll
    for(int k2=0;k2<4;++k2){
      float a  = w1[cc*4+k2];
      float g2 = w2[cc*4+k2];
#pragma unroll
      for(int tl=0; tl<16; ++tl){ acc1[tl] += a*mv[tl+k2]; acc2[tl] += g2*mv[tl+k2]; }
    }
  }
  float bb1 = c1b[i], bb2 = c1b[i+256];
#pragma unroll
  for(int tl=0; tl<16; ++tl){
    int t = t0 + tl;
    if (t < 1027){
      float o1 = acc1[tl] + bb1;
      float o2 = acc2[tl] + bb2;
      h2[((size_t)b*1027 + t)*256 + i] = o1 * silu_f(o2);
    }
  }
}

// ---------------------------------------------------------------------------
// K8: conv2 (flipped d1_w) + 0.5*ff + residuals + LN3 -> out. wave per token.
__global__ __launch_bounds__(256) void k_ff_final(
    const float* __restrict__ h2, const float* __restrict__ d1w, const float* __restrict__ d1b,
    const float* __restrict__ x2, const float* __restrict__ marr,
    const float* __restrict__ ln3w, const float* __restrict__ ln3b,
    float* __restrict__ out){
  int b = blockIdx.y;
  int s0 = blockIdx.x * 4;
  int tid = threadIdx.x;
  int o = tid & 63, sl = tid >> 6;
  __shared__ float hs[7][256];
#pragma unroll
  for(int r2 = 0; r2 < 7; ++r2)
    hs[r2][tid] = h2[((size_t)b*1027 + s0 + r2)*256 + tid];
  __syncthreads();
  int s = s0 + sl;
  float acc = 0.f;
  const float4* wb = (const float4*)d1w + o;   // d1w[i][o][0..3]
#pragma unroll 2
  for(int i2=0; i2<256; ++i2){
    float4 wv = wb[(size_t)i2*64];
    // ff += h2[b,i,s+k] * d1w[i,o,3-k]
    acc += hs[sl+0][i2]*wv.w + hs[sl+1][i2]*wv.z + hs[sl+2][i2]*wv.y + hs[sl+3][i2]*wv.x;
  }
  float ffv = acc + d1b[o];
  size_t idx = ((size_t)b*1024 + s)*64 + o;
  float tot = x2[idx] + marr[idx] + 0.5f*ffv;
  float mean = wsum64(tot)*0.015625f;
  float dlt = tot - mean;
  float var = wsum64(dlt*dlt)*0.015625f;
  out[idx] = dlt*rsqrtf(var+1e-5f)*ln3w[o] + ln3b[o];
}

// ---------------------------------------------------------------------------
extern "C" void kernel_launch(void* const* d_in, const int* in_sizes, int n_in,
                              void* d_out, int out_size, void* d_ws, size_t ws_size,
                              hipStream_t stream){
  const float* x       = (const float*)d_in[0];
  const int*   dmask   = (const int*)  d_in[1];   // bool -> int32 per harness
  const float* ln1w    = (const float*)d_in[2];
  const float* ln1b    = (const float*)d_in[3];
  const float* Wq      = (const float*)d_in[4];
  const float* Wkv     = (const float*)d_in[5];
  const float* Wo      = (const float*)d_in[6];
  const float* bo      = (const float*)d_in[7];
  const float* rel     = (const float*)d_in[8];
  const float* ln2w    = (const float*)d_in[9];
  const float* ln2b    = (const float*)d_in[10];
  const float* W_in    = (const float*)d_in[11];
  const float* conv_w  = (const float*)d_in[12];
  const float* conv_b  = (const float*)d_in[13];
  const float* W_xproj = (const float*)d_in[14];
  const float* W_dt    = (const float*)d_in[15];
  const float* b_dt    = (const float*)d_in[16];
  const float* A_log   = (const float*)d_in[17];
  const float* Dm      = (const float*)d_in[18];
  const float* W_out   = (const float*)d_in[19];
  const float* gamma   = (const float*)d_in[20];
  const float* c1w     = (const float*)d_in[21];
  const float* c1b     = (const float*)d_in[22];
  const float* d1w     = (const float*)d_in[23];
  const float* d1b     = (const float*)d_in[24];
  const float* ln3w    = (const float*)d_in[25];
  const float* ln3b    = (const float*)d_in[26];
  float* outp = (float*)d_out;

  float* ws = (float*)d_ws;
  float* qb       = ws;              // 524288
  float* kb       = qb      + 524288;
  float* vb       = kb      + 524288;
  float* attn_raw = vb      + 524288;
  float* x2       = attn_raw+ 524288;
  float* u0       = x2      + 524288;   // 1048576
  float* zsarr    = u0      + 1048576;
  float* uarr     = zsarr   + 1048576;
  float* dtarr    = uarr    + 1048576;
  float* Bmp      = dtarr   + 1048576;  // 524288
  float* Cmp      = Bmp     + 524288;
  float* ymp      = Cmp     + 524288;   // 1048576
  float* marr     = ymp     + 1048576;  // 524288
  float* h2       = marr    + 524288;   // 8*1027*256 = 2103296

  k_ln1_qkv  <<<2048, 256, 0, stream>>>(x, ln1w, ln1b, Wq, Wkv, qb, kb, vb);
  k_attn     <<<dim3(128,32), 256, 0, stream>>>(qb, kb, vb, dmask, rel, attn_raw);
  k_post_attn<<<2048, 256, 0, stream>>>(x, attn_raw, Wo, bo, ln2w, ln2b, W_in, x2, u0, zsarr);
  k_conv_proj<<<4096, 256, 0, stream>>>(u0, conv_w, conv_b, W_xproj, W_dt, b_dt, uarr, Bmp, Cmp, dtarr);
  k_scan     <<<256, 256, 0, stream>>>(dtarr, uarr, Bmp, Cmp, zsarr, A_log, Dm, ymp);
  k_wout     <<<2048, 256, 0, stream>>>(ymp, W_out, gamma, marr);
  k_h2       <<<dim3(65,8), 256, 0, stream>>>(marr, c1w, c1b, h2);
  k_ff_final <<<dim3(256,8), 256, 0, stream>>>(h2, d1w, d1b, x2, marr, ln3w, ln3b, outp);
}

// Round 2
// 1333.485 us; speedup vs baseline: 1.0792x; 1.0792x over previous
//
#include <hip/hip_runtime.h>
#include <math.h>

// Shapes: B=8, N=1024, D=64, H=4, DH=16, DI=128, DS=64, DTR=4, MAXP=512

__device__ __forceinline__ float wsum64(float v){
#pragma unroll
  for(int m=32;m>0;m>>=1) v += __shfl_xor(v, m, 64);
  return v;
}
__device__ __forceinline__ float wmax64(float v){
#pragma unroll
  for(int m=32;m>0;m>>=1) v = fmaxf(v, __shfl_xor(v, m, 64));
  return v;
}
__device__ __forceinline__ float silu_f(float x){ return x / (1.f + __expf(-x)); }

struct V16 { float4 a,b,c,d; };
__device__ __forceinline__ V16 ld16(const float* p){
  const float4* q = (const float4*)p;
  V16 r; r.a=q[0]; r.b=q[1]; r.c=q[2]; r.d=q[3]; return r;
}
// q . (k + r)
__device__ __forceinline__ float dotqkr(const V16&q, const V16&k, const V16&r){
  return q.a.x*(k.a.x+r.a.x)+q.a.y*(k.a.y+r.a.y)+q.a.z*(k.a.z+r.a.z)+q.a.w*(k.a.w+r.a.w)
       + q.b.x*(k.b.x+r.b.x)+q.b.y*(k.b.y+r.b.y)+q.b.z*(k.b.z+r.b.z)+q.b.w*(k.b.w+r.b.w)
       + q.c.x*(k.c.x+r.c.x)+q.c.y*(k.c.y+r.c.y)+q.c.z*(k.c.z+r.c.z)+q.c.w*(k.c.w+r.c.w)
       + q.d.x*(k.d.x+r.d.x)+q.d.y*(k.d.y+r.d.y)+q.d.z*(k.d.z+r.d.z)+q.d.w*(k.d.w+r.d.w);
}

// ---------------------------------------------------------------------------
// K1: LN1 + Q / KV projection.  wave per token.
__global__ __launch_bounds__(256) void k_ln1_qkv(
    const float* __restrict__ x, const float* __restrict__ w1, const float* __restrict__ b1,
    const float* __restrict__ Wq, const float* __restrict__ Wkv,
    float* __restrict__ qb, float* __restrict__ kb, float* __restrict__ vb){
  int lane = threadIdx.x & 63, warp = threadIdx.x >> 6;
  int token = blockIdx.x*4 + warp;            // 0..8191
  __shared__ float xt[4][64];
  float xv = x[(size_t)token*64 + lane];
  float mean = wsum64(xv) * 0.015625f;
  float dlt = xv - mean;
  float var = wsum64(dlt*dlt) * 0.015625f;
  float xn = dlt * rsqrtf(var + 1e-5f) * w1[lane] + b1[lane];
  xt[warp][lane] = xn;
  __syncthreads();
  float aq=0.f, ak=0.f, av=0.f;
#pragma unroll 4
  for(int dd=0; dd<64; ++dd){
    float xd = xt[warp][dd];
    aq += xd * Wq[dd*64 + lane];
    ak += xd * Wkv[dd*128 + lane];
    av += xd * Wkv[dd*128 + 64 + lane];
  }
  int b = token >> 10, i = token & 1023;
  int h = lane >> 4, dh = lane & 15;
  size_t o = (((size_t)(b*4 + h))*1024 + i)*16 + dh;   // (B,H,N,DH)
  qb[o]=aq; kb[o]=ak; vb[o]=av;
}

// ---------------------------------------------------------------------------
// K2: attention. block = 4 waves; each wave owns 2 query rows end-to-end.
// Lane l owns columns j = l + 64*t, t=0..15: fully coalesced K/V/mask streams,
// scores held in registers, softmax via wave shuffles. No score LDS.
#define TI 8
__global__ __launch_bounds__(256, 4) void k_attn(
    const float* __restrict__ qb, const float* __restrict__ kb, const float* __restrict__ vb,
    const int* __restrict__ dmask, const float* __restrict__ rel,
    float* __restrict__ attn_raw){
  int tid = threadIdx.x;
  int lane = tid & 63, wv = tid >> 6;       // wave 0..3
  int bh  = blockIdx.y;                     // 0..31
  int it0 = blockIdx.x * TI;
  int b = bh >> 2, h = bh & 3;
  int i0 = it0 + 2*wv, i1 = i0 + 1;

  // q rows for this wave (broadcast loads)
  V16 q0 = ld16(qb + ((size_t)bh*1024 + i0)*16);
  V16 q1 = ld16(qb + ((size_t)bh*1024 + i1)*16);

  const float* kbase = kb + (size_t)bh*1024*16;
  const float* vbase = vb + (size_t)bh*1024*16;
  const int*   mbase = dmask + (size_t)bh*1024*1024;

  float s0[16], s1[16];
  float m0 = -3.0e38f, m1 = -3.0e38f;
#pragma unroll
  for(int t=0;t<16;++t){
    int j = lane + 64*t;
    V16 k = ld16(kbase + (size_t)j*16);
    int mk0 = mbase[(size_t)i0*1024 + j];
    int mk1 = mbase[(size_t)i1*1024 + j];
    // row 0
    int d0 = i0 - j; d0 = d0 < -512 ? -512 : (d0 > 512 ? 512 : d0); d0 += 512;
    V16 r0 = ld16(rel + (size_t)d0*16);
    float sv0 = 0.25f*dotqkr(q0, k, r0) + (mk0 ? -1.0e12f : 0.0f);
    s0[t] = sv0; m0 = fmaxf(m0, sv0);
    // row 1
    int d1 = i1 - j; d1 = d1 < -512 ? -512 : (d1 > 512 ? 512 : d1); d1 += 512;
    V16 r1 = ld16(rel + (size_t)d1*16);
    float sv1 = 0.25f*dotqkr(q1, k, r1) + (mk1 ? -1.0e12f : 0.0f);
    s1[t] = sv1; m1 = fmaxf(m1, sv1);
  }
  m0 = wmax64(m0); m1 = wmax64(m1);
  float sum0 = 0.f, sum1 = 0.f;
#pragma unroll
  for(int t=0;t<16;++t){
    s0[t] = __expf(s0[t] - m0); sum0 += s0[t];
    s1[t] = __expf(s1[t] - m1); sum1 += s1[t];
  }
  sum0 = wsum64(sum0); sum1 = wsum64(sum1);

  // PV: acc[c] per row, c = 0..15
  float a0[16], a1[16];
#pragma unroll
  for(int c=0;c<16;++c){ a0[c]=0.f; a1[c]=0.f; }
#pragma unroll
  for(int t=0;t<16;++t){
    int j = lane + 64*t;
    V16 v = ld16(vbase + (size_t)j*16);
    float p0 = s0[t], p1 = s1[t];
    a0[ 0]+=p0*v.a.x; a0[ 1]+=p0*v.a.y; a0[ 2]+=p0*v.a.z; a0[ 3]+=p0*v.a.w;
    a0[ 4]+=p0*v.b.x; a0[ 5]+=p0*v.b.y; a0[ 6]+=p0*v.b.z; a0[ 7]+=p0*v.b.w;
    a0[ 8]+=p0*v.c.x; a0[ 9]+=p0*v.c.y; a0[10]+=p0*v.c.z; a0[11]+=p0*v.c.w;
    a0[12]+=p0*v.d.x; a0[13]+=p0*v.d.y; a0[14]+=p0*v.d.z; a0[15]+=p0*v.d.w;
    a1[ 0]+=p1*v.a.x; a1[ 1]+=p1*v.a.y; a1[ 2]+=p1*v.a.z; a1[ 3]+=p1*v.a.w;
    a1[ 4]+=p1*v.b.x; a1[ 5]+=p1*v.b.y; a1[ 6]+=p1*v.b.z; a1[ 7]+=p1*v.b.w;
    a1[ 8]+=p1*v.c.x; a1[ 9]+=p1*v.c.y; a1[10]+=p1*v.c.z; a1[11]+=p1*v.c.w;
    a1[12]+=p1*v.d.x; a1[13]+=p1*v.d.y; a1[14]+=p1*v.d.z; a1[15]+=p1*v.d.w;
  }
  // partial reduce: lanes {l, l^16, l^32, l^48} -> group g = l&15
#pragma unroll
  for(int c=0;c<16;++c){
    a0[c] += __shfl_xor(a0[c], 32, 64); a0[c] += __shfl_xor(a0[c], 16, 64);
    a1[c] += __shfl_xor(a1[c], 32, 64); a1[c] += __shfl_xor(a1[c], 16, 64);
  }
  __shared__ float red[8][16][17];
  __shared__ float sums[8];
  if (lane < 16){
#pragma unroll
    for(int c=0;c<16;++c){ red[2*wv][lane][c]=a0[c]; red[2*wv+1][lane][c]=a1[c]; }
  }
  if (lane == 0){ sums[2*wv]=sum0; sums[2*wv+1]=sum1; }
  __syncthreads();
  if (tid < 128){
    int row = tid >> 4, c = tid & 15;
    float tot = 0.f;
#pragma unroll
    for(int g=0; g<16; ++g) tot += red[row][g][c];
    int i = it0 + row;
    attn_raw[((size_t)b*1024 + i)*64 + h*16 + c] = tot / sums[row];
  }
}

// ---------------------------------------------------------------------------
// K3: Wo proj + double residual + LN2 + W_in (u0, silu(z)). wave per token.
__global__ __launch_bounds__(256) void k_post_attn(
    const float* __restrict__ x, const float* __restrict__ attn_raw,
    const float* __restrict__ Wo, const float* __restrict__ bo,
    const float* __restrict__ ln2w, const float* __restrict__ ln2b,
    const float* __restrict__ W_in,
    float* __restrict__ x2, float* __restrict__ u0, float* __restrict__ zsarr){
  int lane = threadIdx.x & 63, warp = threadIdx.x >> 6;
  int token = blockIdx.x*4 + warp;
  __shared__ float ar[4][64];
  __shared__ float lnv[4][64];
  ar[warp][lane] = attn_raw[(size_t)token*64 + lane];
  __syncthreads();
  float acc = bo[lane];
#pragma unroll 4
  for(int dd=0;dd<64;++dd) acc += ar[warp][dd]*Wo[dd*64+lane];
  float t = 2.f*x[(size_t)token*64+lane] + acc;    // x + (attn_out + x)
  x2[(size_t)token*64+lane] = t;
  float mean = wsum64(t)*0.015625f;
  float dlt = t-mean;
  float var = wsum64(dlt*dlt)*0.015625f;
  float ln = dlt*rsqrtf(var+1e-5f)*ln2w[lane]+ln2b[lane];
  lnv[warp][lane]=ln;
  __syncthreads();
  float a0=0.f,a1=0.f,a2=0.f,a3=0.f;
#pragma unroll 4
  for(int dd=0;dd<64;++dd){
    float xd = lnv[warp][dd];
    const float* wr = W_in + dd*256;
    a0 += xd*wr[lane]; a1 += xd*wr[lane+64]; a2 += xd*wr[lane+128]; a3 += xd*wr[lane+192];
  }
  u0[(size_t)token*128 + lane] = a0;
  u0[(size_t)token*128 + 64 + lane] = a1;
  zsarr[(size_t)token*128 + lane] = silu_f(a2);
  zsarr[(size_t)token*128 + 64 + lane] = silu_f(a3);
}

// ---------------------------------------------------------------------------
// K4: causal depthwise conv4 + silu + x-proj(132) + softplus dt. 128 lanes/token.
__global__ __launch_bounds__(256) void k_conv_proj(
    const float* __restrict__ u0, const float* __restrict__ conv_w, const float* __restrict__ conv_b,
    const float* __restrict__ W_xproj, const float* __restrict__ W_dt, const float* __restrict__ b_dt,
    float* __restrict__ uarr, float* __restrict__ Bmp, float* __restrict__ Cmp, float* __restrict__ dtarr){
  int sub = threadIdx.x >> 7, c = threadIdx.x & 127;
  int token = blockIdx.x*2 + sub;
  int b = token >> 10, i = token & 1023;
  __shared__ float us[2][128];
  __shared__ float dtin[2][4];
  float acc = conv_b[c];
#pragma unroll
  for(int k2=0;k2<4;++k2){
    int t2 = i - 3 + k2;
    if (t2 >= 0) acc += u0[((size_t)b*1024 + t2)*128 + c]*conv_w[c*4+k2];
  }
  float uv = silu_f(acc);
  uarr[(size_t)token*128 + c] = uv;
  us[sub][c] = uv;
  __syncthreads();
  float accA = 0.f, accB = 0.f;
  int cB = 128 + (c & 3);
#pragma unroll 4
  for(int dd=0; dd<128; ++dd){
    float xd = us[sub][dd];
    accA += xd * W_xproj[dd*132 + c];
    accB += xd * W_xproj[dd*132 + cB];
  }
  if (c < 4){ dtin[sub][c] = accA; Cmp[(size_t)token*64 + 60 + c] = accB; }
  else if (c < 68) Bmp[(size_t)token*64 + (c-4)] = accA;
  else             Cmp[(size_t)token*64 + (c-68)] = accA;
  __syncthreads();
  float dv = b_dt[c];
#pragma unroll
  for(int r2=0;r2<4;++r2) dv += dtin[sub][r2]*W_dt[r2*128 + c];
  dv = fmaxf(dv, 0.f) + log1pf(expf(-fabsf(dv)));   // softplus, stable
  dtarr[(size_t)token*128 + c] = dv;
}

// ---------------------------------------------------------------------------
// K5: selective scan. wave = (b,d), lane = s. 8-step load batching for MLP.
__global__ __launch_bounds__(256) void k_scan(
    const float* __restrict__ dtarr, const float* __restrict__ uarr,
    const float* __restrict__ Bmp, const float* __restrict__ Cmp,
    const float* __restrict__ zsarr, const float* __restrict__ A_log,
    const float* __restrict__ Dm, float* __restrict__ ymp){
  int lane = threadIdx.x & 63, warp = threadIdx.x >> 6;
  int g = blockIdx.x*4 + warp;          // 0..1023
  int b = g >> 7, d = g & 127;
  float A = -expf(A_log[d*64 + lane]);
  float Dv = Dm[d];
  const float* dtp = dtarr + (size_t)b*1024*128 + d;
  const float* up  = uarr  + (size_t)b*1024*128 + d;
  const float* zp  = zsarr + (size_t)b*1024*128 + d;
  const float* Bp  = Bmp   + (size_t)b*1024*64 + lane;
  const float* Cp  = Cmp   + (size_t)b*1024*64 + lane;
  float* yp        = ymp   + (size_t)b*1024*128 + d;
  float h = 0.f;
  for(int t0=0; t0<1024; t0+=8){
    float dtc[8], uc[8], Bc[8], Cc[8], zc[8];
#pragma unroll
    for(int r=0;r<8;++r){
      dtc[r]=dtp[(size_t)(t0+r)*128]; uc[r]=up[(size_t)(t0+r)*128];
      Bc[r]=Bp[(size_t)(t0+r)*64];    Cc[r]=Cp[(size_t)(t0+r)*64];
      zc[r]=zp[(size_t)(t0+r)*128];
    }
#pragma unroll
    for(int r=0;r<8;++r){
      float dt = dtc[r];
      h = h*__expf(dt*A) + dt*uc[r]*Bc[r];
      float y = wsum64(h*Cc[r]);
      if (lane==0) yp[(size_t)(t0+r)*128] = (y + uc[r]*Dv)*zc[r];
    }
  }
}

// ---------------------------------------------------------------------------
// K6: y @ W_out + leaky + group(4)-RMS-norm. wave per token.
__global__ __launch_bounds__(256) void k_wout(
    const float* __restrict__ ymp, const float* __restrict__ W_out,
    const float* __restrict__ gamma, float* __restrict__ marr){
  int lane = threadIdx.x & 63, warp = threadIdx.x >> 6;
  int token = blockIdx.x*4 + warp;
  __shared__ float ys[4][128];
  ys[warp][lane]      = ymp[(size_t)token*128 + lane];
  ys[warp][lane+64]   = ymp[(size_t)token*128 + 64 + lane];
  __syncthreads();
  float acc = 0.f;
#pragma unroll 4
  for(int dd=0; dd<128; ++dd) acc += ys[warp][dd]*W_out[dd*64 + lane];
  acc = acc >= 0.f ? acc : 0.01f*acc;                 // leaky relu
  float ss = acc*acc;
#pragma unroll
  for(int m=1;m<16;m<<=1) ss += __shfl_xor(ss, m, 64); // 16-lane group sum
  float rms = sqrtf(ss)*0.25f;                         // * dpg^-0.5 (dpg=16)
  marr[(size_t)token*64 + lane] = acc/(rms + 1e-5f)*gamma[lane];
}

// ---------------------------------------------------------------------------
// K7: GLU conv1 -> h2[b, tau(0..1026), i(0..255)], tau-major for coalescing.
__global__ __launch_bounds__(256) void k_h2(
    const float* __restrict__ marr, const float* __restrict__ c1w,
    const float* __restrict__ c1b, float* __restrict__ h2){
  int b = blockIdx.y;
  int t0 = blockIdx.x * 16;
  int tid = threadIdx.x;
  __shared__ float ms[19][64];
  for(int l = tid; l < 19*64; l += 256){
    int row = l >> 6, cc = l & 63;
    int t = t0 - 3 + row;
    ms[row][cc] = (t >= 0 && t < 1024) ? marr[((size_t)b*1024 + t)*64 + cc] : 0.f;
  }
  __syncthreads();
  int i = tid;
  float acc1[16], acc2[16];
#pragma unroll
  for(int tl=0;tl<16;++tl){ acc1[tl]=0.f; acc2[tl]=0.f; }
  const float* w1 = c1w + (size_t)i*256;
  const float* w2 = c1w + (size_t)(i+256)*256;
  for(int cc=0; cc<64; ++cc){
    float mv[19];
#pragma unroll
    for(int r2=0;r2<19;++r2) mv[r2] = ms[r2][cc];
#pragma unroll
    for(int k2=0;k2<4;++k2){
      float a  = w1[cc*4+k2];
      float g2 = w2[cc*4+k2];
#pragma unroll
      for(int tl=0; tl<16; ++tl){ acc1[tl] += a*mv[tl+k2]; acc2[tl] += g2*mv[tl+k2]; }
    }
  }
  float bb1 = c1b[i], bb2 = c1b[i+256];
#pragma unroll
  for(int tl=0; tl<16; ++tl){
    int t = t0 + tl;
    if (t < 1027){
      float o1 = acc1[tl] + bb1;
      float o2 = acc2[tl] + bb2;
      h2[((size_t)b*1027 + t)*256 + i] = o1 * silu_f(o2);
    }
  }
}

// ---------------------------------------------------------------------------
// K8: conv2 (flipped d1_w) + 0.5*ff + residuals + LN3 -> out. wave per token.
__global__ __launch_bounds__(256) void k_ff_final(
    const float* __restrict__ h2, const float* __restrict__ d1w, const float* __restrict__ d1b,
    const float* __restrict__ x2, const float* __restrict__ marr,
    const float* __restrict__ ln3w, const float* __restrict__ ln3b,
    float* __restrict__ out){
  int b = blockIdx.y;
  int s0 = blockIdx.x * 4;
  int tid = threadIdx.x;
  int o = tid & 63, sl = tid >> 6;
  __shared__ float hs[7][256];
#pragma unroll
  for(int r2 = 0; r2 < 7; ++r2)
    hs[r2][tid] = h2[((size_t)b*1027 + s0 + r2)*256 + tid];
  __syncthreads();
  int s = s0 + sl;
  float acc = 0.f;
  const float4* wb = (const float4*)d1w + o;   // d1w[i][o][0..3]
#pragma unroll 2
  for(int i2=0; i2<256; ++i2){
    float4 wv = wb[(size_t)i2*64];
    // ff += h2[b,i,s+k] * d1w[i,o,3-k]
    acc += hs[sl+0][i2]*wv.w + hs[sl+1][i2]*wv.z + hs[sl+2][i2]*wv.y + hs[sl+3][i2]*wv.x;
  }
  float ffv = acc + d1b[o];
  size_t idx = ((size_t)b*1024 + s)*64 + o;
  float tot = x2[idx] + marr[idx] + 0.5f*ffv;
  float mean = wsum64(tot)*0.015625f;
  float dlt = tot - mean;
  float var = wsum64(dlt*dlt)*0.015625f;
  out[idx] = dlt*rsqrtf(var+1e-5f)*ln3w[o] + ln3b[o];
}

// ---------------------------------------------------------------------------
extern "C" void kernel_launch(void* const* d_in, const int* in_sizes, int n_in,
                              void* d_out, int out_size, void* d_ws, size_t ws_size,
                              hipStream_t stream){
  const float* x       = (const float*)d_in[0];
  const int*   dmask   = (const int*)  d_in[1];   // bool -> int32 per harness
  const float* ln1w    = (const float*)d_in[2];
  const float* ln1b    = (const float*)d_in[3];
  const float* Wq      = (const float*)d_in[4];
  const float* Wkv     = (const float*)d_in[5];
  const float* Wo      = (const float*)d_in[6];
  const float* bo      = (const float*)d_in[7];
  const float* rel     = (const float*)d_in[8];
  const float* ln2w    = (const float*)d_in[9];
  const float* ln2b    = (const float*)d_in[10];
  const float* W_in    = (const float*)d_in[11];
  const float* conv_w  = (const float*)d_in[12];
  const float* conv_b  = (const float*)d_in[13];
  const float* W_xproj = (const float*)d_in[14];
  const float* W_dt    = (const float*)d_in[15];
  const float* b_dt    = (const float*)d_in[16];
  const float* A_log   = (const float*)d_in[17];
  const float* Dm      = (const float*)d_in[18];
  const float* W_out   = (const float*)d_in[19];
  const float* gamma   = (const float*)d_in[20];
  const float* c1w     = (const float*)d_in[21];
  const float* c1b     = (const float*)d_in[22];
  const float* d1w     = (const float*)d_in[23];
  const float* d1b     = (const float*)d_in[24];
  const float* ln3w    = (const float*)d_in[25];
  const float* ln3b    = (const float*)d_in[26];
  float* outp = (float*)d_out;

  float* ws = (float*)d_ws;
  float* qb       = ws;              // 524288
  float* kb       = qb      + 524288;
  float* vb       = kb      + 524288;
  float* attn_raw = vb      + 524288;
  float* x2       = attn_raw+ 524288;
  float* u0       = x2      + 524288;   // 1048576
  float* zsarr    = u0      + 1048576;
  float* uarr     = zsarr   + 1048576;
  float* dtarr    = uarr    + 1048576;
  float* Bmp      = dtarr   + 1048576;  // 524288
  float* Cmp      = Bmp     + 524288;
  float* ymp      = Cmp     + 524288;   // 1048576
  float* marr     = ymp     + 1048576;  // 524288
  float* h2       = marr    + 524288;   // 8*1027*256 = 2103296

  k_ln1_qkv  <<<2048, 256, 0, stream>>>(x, ln1w, ln1b, Wq, Wkv, qb, kb, vb);
  k_attn     <<<dim3(128,32), 256, 0, stream>>>(qb, kb, vb, dmask, rel, attn_raw);
  k_post_attn<<<2048, 256, 0, stream>>>(x, attn_raw, Wo, bo, ln2w, ln2b, W_in, x2, u0, zsarr);
  k_conv_proj<<<4096, 256, 0, stream>>>(u0, conv_w, conv_b, W_xproj, W_dt, b_dt, uarr, Bmp, Cmp, dtarr);
  k_scan     <<<256, 256, 0, stream>>>(dtarr, uarr, Bmp, Cmp, zsarr, A_log, Dm, ymp);
  k_wout     <<<2048, 256, 0, stream>>>(ymp, W_out, gamma, marr);
  k_h2       <<<dim3(65,8), 256, 0, stream>>>(marr, c1w, c1b, h2);
  k_ff_final <<<dim3(256,8), 256, 0, stream>>>(h2, d1w, d1b, x2, marr, ln3w, ln3b, outp);
}